// Round 1
// baseline (180.137 us; speedup 1.0000x reference)
//
#include <hip/hip_runtime.h>
#include <math.h>

// Problem constants (from setup_inputs): B=32, Q=256, M=128, P=64, C=20 (+1 no-object)
constexpr int kB = 32;
constexpr int kQ = 256;
constexpr int kM = 128;
constexpr int kP = 64;
constexpr int kC = 20;          // num_classes; logits have kC+1 = 21 entries
constexpr int kC1 = kC + 1;

// ---------------------------------------------------------------------------
// Kernel 1: classification cross-entropy.
// One block per batch b (256 threads = Q). Each thread q:
//   - resolve target class via last-write-wins scan over src_idx[b,:]
//   - log-softmax over 21 logits, accumulate -logp
// Block-reduce, one atomicAdd into out[0].
// ---------------------------------------------------------------------------
__global__ __launch_bounds__(kQ) void ce_kernel(const float* __restrict__ logits,
                                                const int* __restrict__ src_idx,
                                                const int* __restrict__ labels,
                                                float* __restrict__ out) {
    const int b = blockIdx.x;
    const int q = threadIdx.x;

    __shared__ int s_idx[kM];
    __shared__ int s_lab[kM];
    if (q < kM) {
        s_idx[q] = src_idx[b * kM + q];
        s_lab[q] = labels[b * kM + q];
    }
    __syncthreads();

    // numpy scatter with duplicate indices: last occurrence wins -> ascending overwrite
    int tc = kC;
    #pragma unroll 4
    for (int m = 0; m < kM; ++m) {
        if (s_idx[m] == q) tc = s_lab[m];
    }

    const float* lp = logits + ((size_t)(b * kQ + q)) * kC1;
    float v[kC1];
    float mx = -1e30f;
    #pragma unroll
    for (int c = 0; c < kC1; ++c) {
        v[c] = lp[c];
        mx = fmaxf(mx, v[c]);
    }
    float se = 0.f;
    #pragma unroll
    for (int c = 0; c < kC1; ++c) se += __expf(v[c] - mx);
    float logp = v[tc] - mx - __logf(se);

    // reduce -logp over the block (4 waves of 64)
    float val = -logp;
    #pragma unroll
    for (int off = 32; off > 0; off >>= 1) val += __shfl_down(val, off, 64);

    __shared__ float wsum[kQ / 64];
    const int lane = q & 63, wid = q >> 6;
    if (lane == 0) wsum[wid] = val;
    __syncthreads();
    if (q == 0) {
        float s = 0.f;
        #pragma unroll
        for (int w = 0; w < kQ / 64; ++w) s += wsum[w];
        atomicAdd(&out[0], s * (1.0f / (float)(kB * kQ)));
    }
}

// ---------------------------------------------------------------------------
// Kernel 2: chamfer polyline loss + direction loss.
// One 64-thread block per (b,m) matched pair. Stage src/tgt polylines (64 pts
// each) in LDS. Lane t computes:
//   minJ = min_j |src[t]-tgt[j]|_1   (row min -> contributes to min2)
//   minI = min_i |src[i]-tgt[t]|_1   (col min -> contributes to min1)
// Wave-reduce sum(minI+minJ); lane 0 adds scaled contribution + direction.
// ---------------------------------------------------------------------------
__global__ __launch_bounds__(kP) void poly_kernel(const float* __restrict__ pred_poly,
                                                  const float* __restrict__ tgt_poly,
                                                  const int* __restrict__ src_idx,
                                                  float* __restrict__ out) {
    const int bm = blockIdx.x;        // 0 .. B*M-1
    const int b = bm / kM;
    const int m = bm - b * kM;
    const int t = threadIdx.x;        // 0..63

    const int sidx = src_idx[b * kM + m];

    __shared__ float sx[kP], sy[kP], tx[kP], ty[kP];
    const float* sp = pred_poly + ((size_t)(b * kQ + sidx)) * kP * 2;
    const float* tp = tgt_poly + ((size_t)bm) * kP * 2;
    sx[t] = sp[2 * t];
    sy[t] = sp[2 * t + 1];
    tx[t] = tp[2 * t];
    ty[t] = tp[2 * t + 1];
    __syncthreads();

    const float mysx = sx[t], mysy = sy[t];
    const float mytx = tx[t], myty = ty[t];

    float minJ = 1e30f;   // min over tgt points for src point t
    float minI = 1e30f;   // min over src points for tgt point t
    #pragma unroll 8
    for (int j = 0; j < kP; ++j) {
        float dJ = fabsf(mysx - tx[j]) + fabsf(mysy - ty[j]);
        minJ = fminf(minJ, dJ);
        float dI = fabsf(sx[j] - mytx) + fabsf(sy[j] - myty);
        minI = fminf(minI, dI);
    }

    float val = minI + minJ;
    #pragma unroll
    for (int off = 32; off > 0; off >>= 1) val += __shfl_down(val, off, 64);

    if (t == 0) {
        // (mean_j minI + mean_i minJ) * 0.5 / (B*M)
        const float scale = 0.5f / ((float)kP * (float)(kB * kM));
        atomicAdd(&out[1], val * scale);

        // direction loss for this pair
        float sdx = sx[kP - 1] - sx[0], sdy = sy[kP - 1] - sy[0];
        float tdx = tx[kP - 1] - tx[0], tdy = ty[kP - 1] - ty[0];
        float sn = sqrtf(sdx * sdx + sdy * sdy) + 1e-6f;
        float tn = sqrtf(tdx * tdx + tdy * tdy) + 1e-6f;
        float cosv = (sdx * tdx + sdy * tdy) / (sn * tn);
        atomicAdd(&out[2], (1.0f - cosv) * (1.0f / (float)(kB * kM)));
    }
}

extern "C" void kernel_launch(void* const* d_in, const int* in_sizes, int n_in,
                              void* d_out, int out_size, void* d_ws, size_t ws_size,
                              hipStream_t stream) {
    const float* pred_logits   = (const float*)d_in[0];
    const float* pred_poly     = (const float*)d_in[1];
    const float* tgt_poly      = (const float*)d_in[2];
    const int*   src_idx       = (const int*)d_in[3];
    const int*   labels        = (const int*)d_in[4];
    float* out = (float*)d_out;

    // d_out is poisoned with 0xAA before every launch — zero it (async, capture-safe)
    hipMemsetAsync(out, 0, (size_t)out_size * sizeof(float), stream);

    ce_kernel<<<kB, kQ, 0, stream>>>(pred_logits, src_idx, labels, out);
    poly_kernel<<<kB * kM, kP, 0, stream>>>(pred_poly, tgt_poly, src_idx, out);
}

// Round 2
// 74.674 us; speedup vs baseline: 2.4123x; 2.4123x over previous
//
#include <hip/hip_runtime.h>
#include <math.h>

// Problem constants: B=32, Q=256, M=128, P=64, C=20 (+1 no-object)
constexpr int kB = 32;
constexpr int kQ = 256;
constexpr int kM = 128;
constexpr int kP = 64;
constexpr int kC = 20;
constexpr int kC1 = kC + 1;

constexpr int kPairsPerBlock = 16;                       // 16 (b,m) pairs per 256-thread block
constexpr int kPolyBlocks   = (kB * kM) / kPairsPerBlock; // 256
constexpr int kCeBlocks     = kB;                         // 32
// ws layout (floats): poly partials [0,1024), dir partials [1024,2048), ce partials [2048,2176)
constexpr int kWsPoly = 0;
constexpr int kWsDir  = 1024;
constexpr int kWsCe   = 2048;

// ---------------------------------------------------------------------------
// Stage 1: fused partial sums, NO global atomics.
// Blocks [0,256): polyline chamfer + direction. Each block stages 16 pairs
//   (src+tgt polylines, float2) into LDS once, then each of the 4 waves
//   computes 4 pairs; per-wave partials written to ws.
// Blocks [256,288): per-batch cross-entropy; per-wave partials to ws.
// ---------------------------------------------------------------------------
__global__ __launch_bounds__(256) void partial_kernel(const float* __restrict__ logits,
                                                      const float2* __restrict__ pred_poly,
                                                      const float2* __restrict__ tgt_poly,
                                                      const int* __restrict__ src_idx,
                                                      const int* __restrict__ labels,
                                                      float* __restrict__ ws) {
    const int tid  = threadIdx.x;
    const int lane = tid & 63;
    const int w    = tid >> 6;

    if (blockIdx.x < kPolyBlocks) {
        __shared__ float2 s_src[kPairsPerBlock][kP];
        __shared__ float2 s_tgt[kPairsPerBlock][kP];
        __shared__ int    s_sidx[kPairsPerBlock];

        const int base = blockIdx.x * kPairsPerBlock;  // global pair base
        const int b    = base >> 7;                    // kM = 128; block never spans b

        if (tid < kPairsPerBlock) s_sidx[tid] = src_idx[base + tid];
        __syncthreads();

        // Stage 16 pairs x (64 src + 64 tgt) float2 = 2048 float2 with 256 threads
        #pragma unroll
        for (int i = 0; i < 8; ++i) {
            const int g      = i * 256 + tid;
            const int p      = g >> 7;
            const int within = g & 127;
            if (within < kP) {
                s_src[p][within] = pred_poly[(size_t)(b * kQ + s_sidx[p]) * kP + within];
            } else {
                s_tgt[p][within - kP] = tgt_poly[(size_t)(base + p) * kP + (within - kP)];
            }
        }
        __syncthreads();

        float accPoly = 0.f, accDir = 0.f;
        #pragma unroll
        for (int i = 0; i < 4; ++i) {
            const int p = w * 4 + i;
            const float2 ms = s_src[p][lane];
            const float2 mt = s_tgt[p][lane];
            float minJ = 1e30f, minI = 1e30f;
            #pragma unroll 8
            for (int j = 0; j < kP; ++j) {
                const float2 sj = s_src[p][j];   // broadcast read — conflict-free
                const float2 tj = s_tgt[p][j];
                minJ = fminf(minJ, fabsf(ms.x - tj.x) + fabsf(ms.y - tj.y));
                minI = fminf(minI, fabsf(sj.x - mt.x) + fabsf(sj.y - mt.y));
            }
            float val = minI + minJ;
            #pragma unroll
            for (int off = 32; off > 0; off >>= 1) val += __shfl_down(val, off, 64);
            if (lane == 0) {
                accPoly += val;
                const float2 s0 = s_src[p][0], s1 = s_src[p][kP - 1];
                const float2 t0 = s_tgt[p][0], t1 = s_tgt[p][kP - 1];
                const float sdx = s1.x - s0.x, sdy = s1.y - s0.y;
                const float tdx = t1.x - t0.x, tdy = t1.y - t0.y;
                const float sn = sqrtf(sdx * sdx + sdy * sdy) + 1e-6f;
                const float tn = sqrtf(tdx * tdx + tdy * tdy) + 1e-6f;
                accDir += 1.0f - (sdx * tdx + sdy * tdy) / (sn * tn);
            }
        }
        if (lane == 0) {
            const int wid = blockIdx.x * 4 + w;  // 0..1023
            ws[kWsPoly + wid] = accPoly;
            ws[kWsDir + wid]  = accDir;
        }
    } else {
        // ---- cross entropy for batch b ----
        const int b = blockIdx.x - kPolyBlocks;
        const int q = tid;
        __shared__ int c_idx[kM];
        __shared__ int c_lab[kM];
        if (tid < kM) {
            c_idx[tid] = src_idx[b * kM + tid];
            c_lab[tid] = labels[b * kM + tid];
        }
        __syncthreads();

        // numpy scatter: last occurrence wins -> ascending overwrite
        int tc = kC;
        #pragma unroll 4
        for (int m = 0; m < kM; ++m) {
            if (c_idx[m] == q) tc = c_lab[m];
        }

        const float* lp = logits + (size_t)(b * kQ + q) * kC1;
        float v[kC1];
        float mx = -1e30f;
        #pragma unroll
        for (int c = 0; c < kC1; ++c) { v[c] = lp[c]; mx = fmaxf(mx, v[c]); }
        float se = 0.f;
        #pragma unroll
        for (int c = 0; c < kC1; ++c) se += __expf(v[c] - mx);
        float val = -(v[tc] - mx - __logf(se));

        #pragma unroll
        for (int off = 32; off > 0; off >>= 1) val += __shfl_down(val, off, 64);
        if (lane == 0) ws[kWsCe + b * 4 + w] = val;  // 128 partials
    }
}

// ---------------------------------------------------------------------------
// Stage 2: single block reduces 1024+1024+128 partials, writes out[0..2].
// ---------------------------------------------------------------------------
__global__ __launch_bounds__(256) void finalize_kernel(const float* __restrict__ ws,
                                                       float* __restrict__ out) {
    const int tid  = threadIdx.x;
    const int lane = tid & 63;
    const int w    = tid >> 6;

    float p = 0.f, d = 0.f, c = 0.f;
    #pragma unroll
    for (int k = 0; k < 4; ++k) {
        p += ws[kWsPoly + tid + 256 * k];
        d += ws[kWsDir + tid + 256 * k];
    }
    if (tid < 128) c = ws[kWsCe + tid];

    #pragma unroll
    for (int off = 32; off > 0; off >>= 1) {
        p += __shfl_down(p, off, 64);
        d += __shfl_down(d, off, 64);
        c += __shfl_down(c, off, 64);
    }

    __shared__ float sp[4], sd[4], sc[4];
    if (lane == 0) { sp[w] = p; sd[w] = d; sc[w] = c; }
    __syncthreads();
    if (tid == 0) {
        const float P = sp[0] + sp[1] + sp[2] + sp[3];
        const float D = sd[0] + sd[1] + sd[2] + sd[3];
        const float C = sc[0] + sc[1] + sc[2] + sc[3];
        out[0] = C * (1.0f / (float)(kB * kQ));
        out[1] = P * (0.5f / ((float)kP * (float)(kB * kM)));
        out[2] = D * (1.0f / (float)(kB * kM));
    }
}

extern "C" void kernel_launch(void* const* d_in, const int* in_sizes, int n_in,
                              void* d_out, int out_size, void* d_ws, size_t ws_size,
                              hipStream_t stream) {
    const float*  pred_logits = (const float*)d_in[0];
    const float2* pred_poly   = (const float2*)d_in[1];
    const float2* tgt_poly    = (const float2*)d_in[2];
    const int*    src_idx     = (const int*)d_in[3];
    const int*    labels      = (const int*)d_in[4];
    float* out = (float*)d_out;
    float* ws  = (float*)d_ws;

    partial_kernel<<<kPolyBlocks + kCeBlocks, 256, 0, stream>>>(
        pred_logits, pred_poly, tgt_poly, src_idx, labels, ws);
    finalize_kernel<<<1, 256, 0, stream>>>(ws, out);
}